// Round 3
// baseline (667.623 us; speedup 1.0000x reference)
//
#include <hip/hip_runtime.h>

// MLPDecoder_Causal: B=8,N=32,T=32,D=4,K=2,H=256,P=4,E=992.
// R8: (a) layer2 MFMA -> fp16 single product (err ~2^-11, slack proven >=0.0156
//     by R6 fp32 absmax) => MFMA time /3, W2 pack /2.
// (b) M=64 (2 bt per block, 1024 blocks) => B-operand L2 traffic /2.
// (c) k_out FUSED into block tail (agg is block-local); Wo1/Wo2 transposed fp16
//     so each thread reads its own contiguous column. Kills the 1-wave/SIMD
//     k_out dispatches + agg ws round trip.
// (d) hooks staged via LDS, stored as contiguous 1KB rows (R7: 64B-granule
//     scatter caused ~50MB of HBM RMW amplification: WRITE 100 vs 67 ideal).
typedef unsigned short u16;
typedef unsigned int   u32;
typedef unsigned long long u64;
typedef __attribute__((ext_vector_type(8))) _Float16 f16x8;
typedef __attribute__((ext_vector_type(4))) float f32x4;

__device__ __forceinline__ float bf2f(u16 s){ u32 u = ((u32)s)<<16; float f; __builtin_memcpy(&f,&u,4); return f; }
__device__ __forceinline__ u16 f2h(float f){ _Float16 h = (_Float16)f; return __builtin_bit_cast(u16, h); }
// generic input accessor (prep only): F=1 -> memory is bf16, F=0 -> fp32
__device__ __forceinline__ float inV(const void* p, int i, int F){
  return F ? bf2f(((const u16*)p)[i]) : ((const float*)p)[i];
}

// wave0 scans first 512 u16 of `inputs`: bf16 N(0,1) data never has exponent
// field >= 0xA0; fp32 low-halves hit that ~37% of the time.
__device__ __forceinline__ void detect_bf16(const void* inputs0, int tid, int* flagL){
  if (tid < 64){
    const uint4* dp = (const uint4*)inputs0;
    uint4 v = dp[tid];
    u32 wds[4] = {v.x, v.y, v.z, v.w};
    int sus = 0;
#pragma unroll
    for (int i2=0; i2<4; ++i2){
      u32 wv = wds[i2];
      u32 h0 = wv & 0xffffu, h1 = wv >> 16;
      if (((h0>>7)&0xffu) >= 0xA0u) sus = 1;
      if (((h1>>7)&0xffu) >= 0xA0u) sus = 1;
    }
    u64 bal = __ballot(sus);
    if (tid == 0) *flagL = (bal == 0ull) ? 1 : 0;
  }
}

// ---------------- workspace layout (bytes) ----------------
#define WS_LAST0 0
#define WS_LAST1 32768
#define WS_WF    65536        // fp32 misc, 8648 floats
#define WS_W2P   102400       // W2 fp16 fragment pack, 131072 u16 = 256KB
#define WS_WO1T  364544       // Wo1^T fp16 [256][264], 135168 B
#define WS_WO2T  499712       // Wo2^T fp16 [256][256], 131072 B

// wf offsets (floats)
#define WF_W1   0             // [k][kd][c]  2*8*256
#define WF_B1   4096          // 2*256
#define WF_B2   4608          // 2*256
#define WF_WO3  5120          // [i][d] 256*4
#define WF_BO1  6144          // 256
#define WF_BO2  6400          // 256
#define WF_BO3  6656          // 4 (+4 pad)
#define WF_EV   6664          // [e][k] 992*2 softmax probs

// prep flat-work partition
#define PR_MISC 6660
#define PR_EV   (PR_MISC + 992)      // 7652
#define PR_L0   (PR_EV + 8192)      // 15844
#define PR_RO   (PR_L0 + 15872)     // 31716
#define PR_W2P  (PR_RO + 131072)    // 162788
#define PR_WO1T (PR_W2P + 67584)    // 230372
#define PR_WO2T (PR_WO1T + 65536)   // 295908

// ---------------- prep: dtype-resolve + pack everything once ----------------
__global__ void k_prep(const void* __restrict__ inputs, const void* __restrict__ rel_graph,
                       const void* __restrict__ gumbel,
                       const void* __restrict__ W1, const void* __restrict__ b1,
                       const void* __restrict__ W2, const void* __restrict__ b2,
                       const void* __restrict__ Wo1, const void* __restrict__ bo1,
                       const void* __restrict__ Wo2, const void* __restrict__ bo2,
                       const void* __restrict__ Wo3, const void* __restrict__ bo3,
                       float* __restrict__ wf, u16* __restrict__ w2p,
                       u16* __restrict__ wo1t, u16* __restrict__ wo2t,
                       float* __restrict__ last0, float* __restrict__ out)
{
  __shared__ int flagL;
  int tid = threadIdx.x;
  detect_bf16(inputs, tid, &flagL);
  __syncthreads();
  const int F = flagL;
  int i = blockIdx.x*256 + tid;
  if (i < PR_MISC){                    // fp32 cache, flat index == wf index
    const void* src; int off;
    if      (i < 4096) { src = W1;  off = i; }
    else if (i < 4608) { src = b1;  off = i-4096; }
    else if (i < 5120) { src = b2;  off = i-4608; }
    else if (i < 6144) { src = Wo3; off = i-5120; }
    else if (i < 6400) { src = bo1; off = i-6144; }
    else if (i < 6656) { src = bo2; off = i-6400; }
    else               { src = bo3; off = i-6656; }
    wf[i] = inV(src, off, F);
    return;
  }
  if (i < PR_EV){                      // softmax((rel+gumbel)/0.5), K=2
    int e = i - PR_MISC;
    float l0 = (inV(rel_graph,2*e,F)   + inV(gumbel,2*e,F))   * 2.f;
    float l1 = (inV(rel_graph,2*e+1,F) + inV(gumbel,2*e+1,F)) * 2.f;
    float m = fmaxf(l0,l1);
    float e0 = __expf(l0-m), e1 = __expf(l1-m), s = 1.f/(e0+e1);
    wf[WF_EV+2*e]   = e0*s;
    wf[WF_EV+2*e+1] = e1*s;
    return;
  }
  if (i < PR_L0){                      // last0[bt][n][d] = inputs[b, n, 4*tp, d]
    int j = i - PR_EV;
    int d = j&3, nn = (j>>2)&31, bt = j>>7, b = bt>>3, tp = bt&7;
    last0[j] = inV(inputs, b*4096 + nn*128 + tp*16 + d, F);
    return;
  }
  if (i < PR_RO){                      // rel_out broadcast
    int j = i - PR_L0;
    out[31744 + j] = inV(rel_graph, j % 1984, F);
    return;
  }
  if (i < PR_W2P){                     // W2 -> fp16 fragment pack
    // flat: (((k*16 + t)*8 + q)*64 + l)*8 + ei
    int e = i - PR_RO;
    int ei = e & 7, l = (e>>3)&63, q = (e>>9)&7, t = (e>>12)&15, k = e>>16;
    int kk  = q*32 + (l>>4)*8 + ei;    // contraction index (h1 col)
    int col = t*16 + (l&15);           // output col
    w2p[e] = f2h(inV(W2, k*65536 + kk*256 + col, F));
    return;
  }
  if (i < PR_WO1T){                    // Wo1^T fp16 [c][264], pad i>=260 -> 0
    int e = i - PR_W2P;
    int c = e / 264, ii = e - c*264;
    wo1t[e] = (ii < 260) ? f2h(inV(Wo1, ii*256 + c, F)) : (u16)0;
    return;
  }
  if (i < PR_WO2T){                    // Wo2^T fp16 [c][256]
    int e = i - PR_WO1T;
    int c = e >> 8, ii = e & 255;
    wo2t[e] = f2h(inV(Wo2, ii*256 + c, F));
  }
}

// ---------------- k_fused: edge MLP + aggregate + output MLP ----------------
__device__ __forceinline__ void fma4(float4& a, float s, float4 w){
  a.x += s*w.x; a.y += s*w.y; a.z += s*w.z; a.w += s*w.w;
}
__device__ __forceinline__ float f4e(const float4& v, int e){  // e compile-time
  switch(e){ case 0: return v.x; case 1: return v.y; case 2: return v.z; default: return v.w; }
}

// block = (bt-pair, receiver n); M=64 rows (2x {31 edges + pad}), N=256, K=256.
// LDS overlay: [0,2048) xj[64][8] | [2048,2304) evL[32][2] |
// [2304,+33280) union{ AhF uint4[32][64] ; hookT f32[32][260] ; tail bufs }
__global__ __launch_bounds__(256, 4) void k_fused(
    const float* __restrict__ lastIn, float* __restrict__ lastOut,
    const float* __restrict__ wf, const u16* __restrict__ w2p,
    const u16* __restrict__ wo1t, const u16* __restrict__ wo2t,
    float* __restrict__ hooks, float* __restrict__ out0, int pstep)
{
  __shared__ __align__(16) char smemRaw[35584];
  float (*xj)[8]  = (float(*)[8])smemRaw;
  float (*evL)[2] = (float(*)[2])(smemRaw + 2048);
  uint4* AhF   = (uint4*)(smemRaw + 2304);     // [ (rt*8+q)*64 + slot ]
  float* hookT = (float*)(smemRaw + 2304);     // [ row*260 + col ]
  float* augT  = (float*)(smemRaw + 2304);     // [ h*264 + i ]
  float* o1T   = (float*)(smemRaw + 2304 + 2112);
  float* o2T   = (float*)(smemRaw + 2304 + 4224);

  const int tid = threadIdx.x;
  const int n = blockIdx.x & 31, btp = blockIdx.x >> 5;
  const int rg = tid & 7, cgi = tid >> 3, c = cgi*8;
  const int lane = tid & 63, wave = tid >> 6;
  const int l15 = lane & 15, lg = lane >> 4;

  if (tid < 64){                   // xj staging: row tid = [send(4)|recv(4)]
    int e = tid & 31, h = tid >> 5, bt = btp*2 + h;
    float4 sv = make_float4(0.f,0.f,0.f,0.f), rv = sv;
    if (e < 31){
      int s = e + (e >= n);
      sv = *(const float4*)&lastIn[bt*128 + s*4];
      rv = *(const float4*)&lastIn[bt*128 + n*4];
    }
    *(float4*)&xj[tid][0] = sv;
    *(float4*)&xj[tid][4] = rv;
  } else if (tid < 95){            // edge softmax (same for both bt)
    int e = tid - 64;
    evL[e][0] = wf[WF_EV + 2*(n*31+e)];
    evL[e][1] = wf[WF_EV + 2*(n*31+e) + 1];
  }
  __syncthreads();

  float agg2[2][4] = {{0.f,0.f,0.f,0.f},{0.f,0.f,0.f,0.f}};

  for (int k=0; k<2; ++k){
    // ---- layer1 fp32 VALU: h1 = relu(x @ W1[k] + b1[k]); thread = 8 rows x 8 cols
    float4 a[8][2];
    {
      float4 bb0 = *(const float4*)&wf[WF_B1 + k*256 + c];
      float4 bb1 = *(const float4*)&wf[WF_B1 + k*256 + c + 4];
#pragma unroll
      for (int ri=0; ri<8; ++ri){ a[ri][0] = bb0; a[ri][1] = bb1; }
      const float* W1k = wf + WF_W1 + k*2048;
#pragma unroll
      for (int hf=0; hf<2; ++hf){
        float4 xr[4][2];
#pragma unroll
        for (int ri=0; ri<4; ++ri){
          int j = rg + 8*(hf*4+ri);
          xr[ri][0] = *(const float4*)&xj[j][0];
          xr[ri][1] = *(const float4*)&xj[j][4];
        }
#pragma unroll
        for (int kd=0; kd<8; ++kd){
          float4 w0 = *(const float4*)&W1k[kd*256 + c];
          float4 w1 = *(const float4*)&W1k[kd*256 + c + 4];
#pragma unroll
          for (int ri=0; ri<4; ++ri){
            float xv = f4e(xr[ri][kd>>2], kd&3);
            fma4(a[hf*4+ri][0], xv, w0); fma4(a[hf*4+ri][1], xv, w1);
          }
        }
      }
    }
    if (k) __syncthreads();        // all k=0 frag reads done before overwrite
    // ---- relu + cvt fp16, store A-frags (lane-linear layout)
#pragma unroll
    for (int ri=0; ri<8; ++ri){
      int j = rg + 8*ri;
      f16x8 hv;
#pragma unroll
      for (int e2=0; e2<8; ++e2)
        hv[e2] = (_Float16)fmaxf(f4e(a[ri][e2>>2], e2&3), 0.f);
      int fi   = ((j>>4)<<3) + (cgi>>2);       // rt*8 + q
      int slot = (j&15) + ((cgi&3)<<4);
      AhF[fi*64 + slot] = __builtin_bit_cast(uint4, hv);
    }
    __syncthreads();               // frags ready

    // ---- layer2 MFMA fp16: acc(+b2) += A * B;  16 independent acc chains
    f32x4 acc[4][4];
#pragma unroll
    for (int nt=0; nt<4; ++nt){
      float bv = wf[WF_B2 + k*256 + (wave<<6) + (nt<<4) + l15];
      f32x4 bi = {bv,bv,bv,bv};
#pragma unroll
      for (int rt=0; rt<4; ++rt) acc[rt][nt] = bi;
    }
    const u16* Bbase = w2p + ((k*16 + (wave<<2))*8)*512 + (lane<<3);
#pragma unroll
    for (int q=0; q<8; ++q){
      uint4 Au[4];
#pragma unroll
      for (int rt=0; rt<4; ++rt) Au[rt] = AhF[(rt*8+q)*64 + lane];
#pragma unroll
      for (int nt=0; nt<4; ++nt){
        f16x8 Bf = __builtin_bit_cast(f16x8, *(const uint4*)(Bbase + nt*4096 + q*512));
#pragma unroll
        for (int rt=0; rt<4; ++rt)
          acc[rt][nt] = __builtin_amdgcn_mfma_f32_16x16x32_f16(
              __builtin_bit_cast(f16x8, Au[rt]), Bf, acc[rt][nt], 0,0,0);
      }
    }

    // ---- epilogue: relu * ev; agg partials; hooks (k=1) via LDS transpose
    // D layout: row = 16*rt + 4*lg + r, col = 64*wave + 16*nt + l15
    if (k == 0){
#pragma unroll
      for (int rt=0; rt<4; ++rt){
#pragma unroll
        for (int r=0; r<4; ++r){
          int lr = ((rt&1)<<4) + (lg<<2) + r;
          if (lr < 31){
            float ev = evL[lr][0];
#pragma unroll
            for (int nt=0; nt<4; ++nt)
              agg2[rt>>1][nt] += fmaxf(acc[rt][nt][r], 0.f)*ev;
          }
        }
      }
    } else {
      __syncthreads();             // MFMA ds_reads done -> AhF reusable as hookT
#pragma unroll
      for (int h=0; h<2; ++h){
#pragma unroll
        for (int rt2=0; rt2<2; ++rt2){
          int rt = h*2 + rt2;
#pragma unroll
          for (int r=0; r<4; ++r){
            int lr = (rt2<<4) + (lg<<2) + r;
            if (lr < 31){
              float ev = evL[lr][1];
#pragma unroll
              for (int nt=0; nt<4; ++nt){
                float m = fmaxf(acc[rt][nt][r], 0.f)*ev;
                agg2[h][nt] += m;
                hookT[lr*260 + (wave<<6) + (nt<<4) + l15] = m;
              }
            }
          }
        }
        __syncthreads();           // hookT chunk complete
        {
          int bt = btp*2 + h, bb = bt>>3, tp = bt&7;
          int hbh = (((pstep*8 + tp)*8 + bb)*992 + n*31)*256;
#pragma unroll
          for (int it=0; it<8; ++it){
            int row = wave + (it<<2);          // wave-uniform
            if (row < 31){
              float4 v = *(const float4*)&hookT[row*260 + (lane<<2)];
              *(float4*)&hooks[hbh + row*256 + (lane<<2)] = v;
            }
          }
        }
        __syncthreads();           // stores read out before next chunk / tail
      }
    }
  }

  // ---- aggregate across lane-groups; build aug = [last(4) | agg(256)]
#pragma unroll
  for (int h=0; h<2; ++h)
#pragma unroll
    for (int nt=0; nt<4; ++nt){
      float v = agg2[h][nt];
      v += __shfl_xor(v, 16);
      v += __shfl_xor(v, 32);
      agg2[h][nt] = v;
    }
  if (lg == 0){
#pragma unroll
    for (int h=0; h<2; ++h)
#pragma unroll
      for (int nt=0; nt<4; ++nt)
        augT[h*264 + 4 + (wave<<6) + (nt<<4) + l15] = agg2[h][nt];
  }
  if (tid < 8){
    int h = tid>>2, d = tid&3;
    augT[h*264 + d] = lastIn[(btp*2+h)*128 + n*4 + d];
  } else if (tid < 16){
    int h = (tid-8)>>2, d = (tid-8)&3;
    augT[h*264 + 260 + d] = 0.f;   // pad (Wo1T pad weights are 0, avoid NaN*0)
  }
  __syncthreads();

  // ---- output MLP: thread = col; both rows share the loaded weight column
  {
    const u16* wc = wo1t + tid*264;
    float s0 = wf[WF_BO1 + tid], s1 = s0;
    for (int i=0; i<264; i+=8){
      f16x8 hw = __builtin_bit_cast(f16x8, *(const uint4*)(wc + i));
      float4 xa0 = *(const float4*)&augT[i];
      float4 xa1 = *(const float4*)&augT[i+4];
      float4 xb0 = *(const float4*)&augT[264+i];
      float4 xb1 = *(const float4*)&augT[264+i+4];
      float w0=(float)hw[0], w1=(float)hw[1], w2=(float)hw[2], w3=(float)hw[3];
      float w4=(float)hw[4], w5=(float)hw[5], w6=(float)hw[6], w7=(float)hw[7];
      s0 += xa0.x*w0 + xa0.y*w1 + xa0.z*w2 + xa0.w*w3
          + xa1.x*w4 + xa1.y*w5 + xa1.z*w6 + xa1.w*w7;
      s1 += xb0.x*w0 + xb0.y*w1 + xb0.z*w2 + xb0.w*w3
          + xb1.x*w4 + xb1.y*w5 + xb1.z*w6 + xb1.w*w7;
    }
    o1T[tid] = fmaxf(s0, 0.f); o1T[264 + tid] = fmaxf(s1, 0.f);
  }
  __syncthreads();
  {
    const u16* wc = wo2t + tid*256;
    float s0 = wf[WF_BO2 + tid], s1 = s0;
    for (int i=0; i<256; i+=8){
      f16x8 hw = __builtin_bit_cast(f16x8, *(const uint4*)(wc + i));
      float4 xa0 = *(const float4*)&o1T[i];
      float4 xa1 = *(const float4*)&o1T[i+4];
      float4 xb0 = *(const float4*)&o1T[264+i];
      float4 xb1 = *(const float4*)&o1T[264+i+4];
      float w0=(float)hw[0], w1=(float)hw[1], w2=(float)hw[2], w3=(float)hw[3];
      float w4=(float)hw[4], w5=(float)hw[5], w6=(float)hw[6], w7=(float)hw[7];
      s0 += xa0.x*w0 + xa0.y*w1 + xa0.z*w2 + xa0.w*w3
          + xa1.x*w4 + xa1.y*w5 + xa1.z*w6 + xa1.w*w7;
      s1 += xb0.x*w0 + xb0.y*w1 + xb0.z*w2 + xb0.w*w3
          + xb1.x*w4 + xb1.y*w5 + xb1.z*w6 + xb1.w*w7;
    }
    o2T[tid] = fmaxf(s0, 0.f); o2T[264 + tid] = fmaxf(s1, 0.f);
  }
  __syncthreads();
  if (tid < 128){                  // p = o2 @ Wo3 + bo3; residual; store
    int h = tid>>6, d = tid&3, ch = (tid>>2)&15;
    float p = 0.f;
#pragma unroll
    for (int ii=0; ii<16; ++ii){
      int i = ch*16 + ii;
      p += o2T[h*264 + i]*wf[WF_WO3 + i*4 + d];
    }
    p += __shfl_xor(p, 4); p += __shfl_xor(p, 8);
    p += __shfl_xor(p, 16); p += __shfl_xor(p, 32);
    if (ch == 0){
      int bt = btp*2 + h;
      float lv = lastIn[bt*128 + n*4 + d] + p + wf[WF_BO3 + d];
      lastOut[bt*128 + n*4 + d] = lv;
      int bb = bt>>3, tp = bt&7, t = tp*4 + pstep;
      if (t < 31) out0[bb*3968 + n*124 + t*4 + d] = lv;
    }
  }
}

extern "C" void kernel_launch(void* const* d_in, const int* in_sizes, int n_in,
                              void* d_out, int out_size, void* d_ws, size_t ws_size,
                              hipStream_t stream) {
  const void* inputs    = d_in[0];
  const void* rel_graph = d_in[1];
  const void* W1  = d_in[2];
  const void* b1  = d_in[3];
  const void* W2  = d_in[4];
  const void* b2  = d_in[5];
  const void* Wo1 = d_in[6];
  const void* bo1 = d_in[7];
  const void* Wo2 = d_in[8];
  const void* bo2 = d_in[9];
  const void* Wo3 = d_in[10];
  const void* bo3 = d_in[11];
  const void* gumbel = d_in[14];
  float* out = (float*)d_out;
  char* ws = (char*)d_ws;
  float* L0   = (float*)(ws + WS_LAST0);
  float* L1   = (float*)(ws + WS_LAST1);
  float* wf   = (float*)(ws + WS_WF);
  u16*   w2p  = (u16*)  (ws + WS_W2P);
  u16*   wo1t = (u16*)  (ws + WS_WO1T);
  u16*   wo2t = (u16*)  (ws + WS_WO2T);

  k_prep<<<(PR_WO2T + 255)/256, 256, 0, stream>>>(
      inputs, rel_graph, gumbel, W1, b1, W2, b2, Wo1, bo1, Wo2, bo2, Wo3, bo3,
      wf, w2p, wo1t, wo2t, L0, out);
  for (int p = 0; p < 4; ++p) {
    const float* lin  = (p & 1) ? L1 : L0;
    float*       lout = (p & 1) ? L0 : L1;
    k_fused<<<1024, 256, 0, stream>>>(lin, lout, wf, w2p, wo1t, wo2t,
                                      out + 47616, out, p);
  }
}